// Round 12
// baseline (293.890 us; speedup 1.0000x reference)
//
#include <hip/hip_runtime.h>
#include <math.h>

typedef unsigned short u16;
typedef unsigned int   u32;
typedef unsigned long long u64;

#define T_PRED 30
#define BN 2048
#define DD 256
#define DHH 128
#define ESHIFT 64.0f

typedef __attribute__((ext_vector_type(8))) short short8;   // 8 x bf16
typedef __attribute__((ext_vector_type(4))) float f32x4;

// exp(v - ESHIFT) as one fma + one v_exp  (fallback: sub+mul+exp)
#if defined(__has_builtin)
#if __has_builtin(__builtin_amdgcn_exp2f)
#define EXPSH(v) __builtin_amdgcn_exp2f(__builtin_fmaf((v), 1.44269504f, -92.3324826f))
#endif
#endif
#ifndef EXPSH
#define EXPSH(v) __expf((v) - ESHIFT)
#endif

// ---- workspace layout (~38.3 MB) ----
// 0: f32 nce_acc | 8: u32 done
#define WS_S      4096                     // f32 S[30][2048] fixed-shift exp sums
#define WS_TABLE  (WS_S + 245760)          // u64 table[2048]
#define WS_ZEND   (WS_TABLE + 16384)       // end of zeroed region = 266240 B
#define WS_WH     WS_ZEND                  // u16 W^T hi [30][128][256]
#define WS_WL     (WS_WH + 1966080)        // u16 W^T lo (t=29 slot used)
#define WS_RH     (WS_WL + 1966080)        // u16 rep hi [2048][128]
#define WS_RL     (WS_RH + 524288)
#define WS_GH     (WS_RL + 524288)         // u16 G hi [30][2048][128]
#define WS_GL29   (WS_GH + 15728640)       // u16 G lo (t=29) [2048][128]
#define WS_T29    (WS_GL29 + 524288)       // f32 tot29 [2048][2048]

__device__ __forceinline__ u16 bf16_rne(float f) {
    u32 u = __float_as_uint(f);
    u32 r = u + 0x7fffu + ((u >> 16) & 1u);
    return (u16)(r >> 16);
}

__device__ __forceinline__ short8 pack_hi8(const float* f) {   // truncation split
    short8 r;
#pragma unroll
    for (int k = 0; k < 8; ++k) r[k] = (short)(u16)(__float_as_uint(f[k]) >> 16);
    return r;
}
__device__ __forceinline__ short8 pack_lo8(const float* f) {
    short8 r;
#pragma unroll
    for (int k = 0; k < 8; ++k) {
        float hf = __uint_as_float(__float_as_uint(f[k]) & 0xffff0000u);
        r[k] = (short)bf16_rne(f[k] - hf);
    }
    return r;
}

#define AS1 __attribute__((address_space(1)))
#define AS3 __attribute__((address_space(3)))

// ---------------- prep: zero accumulators + W transpose/split + rep split --
__global__ __launch_bounds__(256) void prep_kernel(
    const float* __restrict__ rep, const float* __restrict__ Ww,
    u16* __restrict__ Rh, u16* __restrict__ Rl,
    u16* __restrict__ Wh, u16* __restrict__ Wl, u32* __restrict__ wsz)
{
    const int bx = blockIdx.x, tid = threadIdx.x;
    // zero nce_acc/done/S/table: 266240 B = 66560 words over 32768 threads
    for (int i = bx * 256 + tid; i < 66560; i += 32768) wsz[i] = 0;

    if (bx < 120) {
        __shared__ float tile[64][132];
        const int t = bx >> 2, d0 = (bx & 3) * 64;
        for (int it = 0; it < 8; ++it) {
            int idx = tid + it * 256;
            int row = idx >> 5, off = (idx & 31) * 4;
            *(float4*)&tile[row][off] =
                *(const float4*)&Ww[((size_t)t * DD + d0 + row) * DHH + off];
        }
        __syncthreads();
        const int h = tid >> 1, half = tid & 1;    // h 0..127, d-half 0..1
        const bool lo = (t == T_PRED - 1);
        for (int d4 = 0; d4 < 32; d4 += 4) {
            ushort4 hv, lv;
            u16* hp = (u16*)&hv; u16* lp = (u16*)&lv;
#pragma unroll
            for (int k = 0; k < 4; ++k) {
                float v = tile[half * 32 + d4 + k][h];
                u16 hb = bf16_rne(v);
                hp[k] = hb;
                float hf = __uint_as_float((u32)hb << 16);
                lp[k] = bf16_rne(v - hf);
            }
            size_t o = (size_t)t * DHH * DD + (size_t)h * DD + d0 + half * 32 + d4;
            *(ushort4*)&Wh[o] = hv;
            if (lo) *(ushort4*)&Wl[o] = lv;
        }
    } else {
        int base = (bx - 120) * 256 + tid;            // float4 index, 8 blocks
        for (int p = 0; p < 32; ++p) {
            int i = base + p * 2048;
            float4 v = ((const float4*)rep)[i];
            float vv[4] = {v.x, v.y, v.z, v.w};
            u16 h[4], l[4];
#pragma unroll
            for (int k = 0; k < 4; ++k) {
                h[k] = bf16_rne(vv[k]);
                float hf = __uint_as_float((u32)h[k] << 16);
                l[k] = bf16_rne(vv[k] - hf);
            }
            ((ushort4*)Rh)[i] = make_ushort4(h[0], h[1], h[2], h[3]);
            ((ushort4*)Rl)[i] = make_ushort4(l[0], l[1], l[2], l[3]);
        }
    }
}

// ---------------- g_fused v4: single-barrier, 128KB LDS, 512 thr -----------
// nce-style restructure: stage W[t] hi (64KB, global_load_lds, rotate-swz)
// and E-block hi (f32 coalesced reg-load -> bf16 pack -> ds_write, rotate-
// swz) ONCE; one __syncthreads; then 8 waves x (16 rows x 128 cols) with
// zero barriers, pre-packed operands, 8 ds_read + 8 MFMA per kc.
// Avoids R2's failure (E loads fully coalesced) and R5's (64 MFMA/wave/kc).
// y<29: main path. y==29: t29 hi/lo 3-MFMA (R1 math, 512-thr geometry).
// grid (16, 30).
__global__ __launch_bounds__(512, 2) void g_fused_kernel(
    const float* __restrict__ E, const u16* __restrict__ Wh,
    const u16* __restrict__ Wl, u16* __restrict__ Gh,
    u16* __restrict__ Gh29, u16* __restrict__ Gl29)
{
    __shared__ __attribute__((aligned(16))) u16 sm[65536];   // 128 KB
    const int y    = blockIdx.y;
    const int bx   = blockIdx.x;
    const int tid  = threadIdx.x;
    const int lane = tid & 63;
    const int w    = tid >> 6;        // 0..7
    const int ml   = lane & 15;
    const int quad = lane >> 4;
    const int r0   = bx << 7;         // 128 rows per block

    if (y < 29) {
        const int t = y;
        const float* Et = E + (size_t)t * BN * DD;
        const u16*   Wt = Wh + (size_t)t * DHH * DD;

        // ---- stage W[t] hi -> wsm (sm+32768), rotate-swizzled ----
        // 16B unit u of col c stored at slot (u + 2c)&31
#pragma unroll
        for (int n = 0; n < 8; ++n) {
            const int q    = (w << 3) + n;       // 0..63 wave-instrs
            const int U    = (q << 6) | lane;    // 0..4095 units
            const int col  = U >> 5;             // 0..127
            const int g    = ((U & 31) - 2 * col) & 31;
            const u16* src = Wt + (size_t)col * DD + g * 8;
            __builtin_amdgcn_global_load_lds((const AS1 u32*)src,
                (AS3 u32*)(&sm[32768 + (q << 9)]), 16, 0, 0);
        }
        // ---- stage E-block hi -> esm (sm), coalesced f32 loads ----
#pragma unroll
        for (int k = 0; k < 16; ++k) {
            const int idx  = tid + (k << 9);     // 0..8191 float4s
            const int row  = idx >> 6;           // 0..127
            const int col4 = idx & 63;           // float4 within row
            float4 v = *(const float4*)(Et + (size_t)(r0 + row) * DD + (col4 << 2));
            ushort4 h;
            h.x = (u16)(__float_as_uint(v.x) >> 16);
            h.y = (u16)(__float_as_uint(v.y) >> 16);
            h.z = (u16)(__float_as_uint(v.z) >> 16);
            h.w = (u16)(__float_as_uint(v.w) >> 16);
            const int slot = ((col4 >> 1) + 2 * row) & 31;
            *(ushort4*)&sm[(row << 8) + (slot << 3) + ((col4 & 1) << 2)] = h;
        }

        __syncthreads();                 // the only barrier

        // ---- compute: wave w -> rows r0+w*16..+16, cols 0..127 ----
        short8 ah[8];
#pragma unroll
        for (int kc = 0; kc < 8; ++kc) {
            const int row  = (w << 4) + ml;
            const int slot = ((kc << 2) + quad + 2 * row) & 31;
            ah[kc] = *(const short8*)&sm[(row << 8) + (slot << 3)];
        }
        f32x4 acc[8];
#pragma unroll
        for (int j = 0; j < 8; ++j) acc[j] = (f32x4){0.f, 0.f, 0.f, 0.f};

#pragma unroll 1
        for (int kc = 0; kc < 8; ++kc) {
#pragma unroll
            for (int j = 0; j < 8; ++j) {
                const int col  = (j << 4) + ml;
                const int slot = ((kc << 2) + quad + 2 * col) & 31;
                const short8 bh = *(const short8*)&sm[32768 + (col << 8) + (slot << 3)];
                acc[j] = __builtin_amdgcn_mfma_f32_16x16x32_bf16(ah[kc], bh, acc[j], 0, 0, 0);
            }
        }

#pragma unroll
        for (int j = 0; j < 8; ++j)
#pragma unroll
            for (int r = 0; r < 4; ++r) {
                const int row = r0 + (w << 4) + (quad << 2) + r;
                Gh[((size_t)t * BN + row) * DHH + (j << 4) + ml] = bf16_rne(acc[j][r]);
            }
    } else {
        // ---- t=29: hi/lo 3-MFMA, wave w -> rows r0+w*16..+16, 128 cols ----
        const size_t tE = (size_t)(T_PRED - 1) * BN * DD;
        const size_t tW = (size_t)(T_PRED - 1) * DHH * DD;

        f32x4 acc[8];
#pragma unroll
        for (int j = 0; j < 8; ++j) acc[j] = (f32x4){0.f, 0.f, 0.f, 0.f};

#pragma unroll 1
        for (int kc = 0; kc < 8; ++kc) {
            const float* ep = E + tE + (size_t)(r0 + (w << 4) + ml) * DD
                              + (kc << 5) + (quad << 3);
            float4 e0 = *(const float4*)ep;
            float4 e1 = *(const float4*)(ep + 4);
            float f[8] = {e0.x, e0.y, e0.z, e0.w, e1.x, e1.y, e1.z, e1.w};
            short8 ahh = pack_hi8(f);
            short8 all = pack_lo8(f);
#pragma unroll
            for (int j = 0; j < 8; ++j) {
                size_t o = tW + (size_t)((j << 4) + ml) * DD + (kc << 5) + (quad << 3);
                short8 bh = *(const short8*)(Wh + o);
                short8 bl = *(const short8*)(Wl + o);
                acc[j] = __builtin_amdgcn_mfma_f32_16x16x32_bf16(ahh, bh, acc[j], 0, 0, 0);
                acc[j] = __builtin_amdgcn_mfma_f32_16x16x32_bf16(ahh, bl, acc[j], 0, 0, 0);
                acc[j] = __builtin_amdgcn_mfma_f32_16x16x32_bf16(all, bh, acc[j], 0, 0, 0);
            }
        }

#pragma unroll
        for (int j = 0; j < 8; ++j)
#pragma unroll
            for (int r = 0; r < 4; ++r) {
                const int row = r0 + (w << 4) + (quad << 2) + r;
                const int col = (j << 4) + ml;
                float v = acc[j][r];
                u16 hb = bf16_rne(v);
                float hf = __uint_as_float((u32)hb << 16);
                Gh29[(size_t)row * DHH + col] = hb;
                Gl29[(size_t)row * DHH + col] = bf16_rne(v - hf);
            }
    }
}

// ---------------- nce_fused v9 (best measured: 52.6us) ---------------------
// 512-thr, grid (8,8,33), 64KB LDS, single stage + single barrier.
// r0 <- blockIdx.x / c0 <- blockIdx.y: XCD-locality swizzle (FETCH 64->14MB).
// Frozen: all intra-block variants measured equal or worse (R3,R5-R8,R10).
__global__ __launch_bounds__(512, 4) void nce_fused_kernel(
    const u16* __restrict__ Gh, const u16* __restrict__ Gh29,
    const u16* __restrict__ Gl29, const u16* __restrict__ Rh,
    const u16* __restrict__ Rl, float* __restrict__ S,
    float* __restrict__ tot29, float* __restrict__ nce_acc)
{
    __shared__ __attribute__((aligned(16))) u16 sm[32768];   // 64 KB
    const int z    = blockIdx.z;
    const int tid  = threadIdx.x;
    const int lane = tid & 63;
    const int w    = tid >> 6;          // 0..7
    const int ml   = lane & 15;
    const int quad = lane >> 4;
    float* S29 = S + (size_t)(T_PRED - 1) * BN;

    if (z < 29) {
        const int t  = z;
        const int c0 = (int)blockIdx.y << 8;     // col block (256)
        const int r0 = (int)blockIdx.x << 8;     // row block (256)

        // ---- stage Rh[c0..c0+256) -> LDS, rotate-swizzled, once ----
#pragma unroll
        for (int n = 0; n < 8; ++n) {
            const int q   = (w << 3) + n;        // 0..63 wave-instrs
            const int U   = (q << 6) | lane;     // 0..4095
            const int col = U >> 4;
            const int g   = ((U & 15) - col) & 15;
            const u16* src = Rh + (size_t)(c0 + col) * DHH + g * 8;
            __builtin_amdgcn_global_load_lds((const AS1 u32*)src,
                (AS3 u32*)(&sm[q << 9]), 16, 0, 0);
        }

        // ---- A fragments: 32 rows/wave, held in registers ----
        short8 ah[2][4];
#pragma unroll
        for (int i = 0; i < 2; ++i)
#pragma unroll
            for (int kc = 0; kc < 4; ++kc)
                ah[i][kc] = *(const short8*)(Gh +
                    ((size_t)t * BN + r0 + (w << 5) + (i << 4) + ml) * DHH
                    + (kc << 5) + (quad << 3));

        float ssum[2][4];
#pragma unroll
        for (int i = 0; i < 2; ++i)
#pragma unroll
            for (int r = 0; r < 4; ++r) ssum[i][r] = 0.f;
        float dsum = 0.f;
        const bool dblk = (c0 == r0);
        const int rbase = r0 + (w << 5) + (quad << 2);   // + i*16 + r

        __syncthreads();                 // the only barrier

#pragma unroll 2
        for (int ch = 0; ch < 8; ++ch) {
            f32x4 acc[2][2];
#pragma unroll
            for (int i = 0; i < 2; ++i)
#pragma unroll
                for (int j = 0; j < 2; ++j) acc[i][j] = (f32x4){0.f, 0.f, 0.f, 0.f};

#pragma unroll
            for (int kc = 0; kc < 4; ++kc) {
                const int slot = ((kc << 2) + quad + ml) & 15;
                const short8 bh0 = *(const short8*)&sm[((ch << 5) + ml) * 128 + (slot << 3)];
                const short8 bh1 = *(const short8*)&sm[((ch << 5) + 16 + ml) * 128 + (slot << 3)];
                acc[0][0] = __builtin_amdgcn_mfma_f32_16x16x32_bf16(ah[0][kc], bh0, acc[0][0], 0, 0, 0);
                acc[0][1] = __builtin_amdgcn_mfma_f32_16x16x32_bf16(ah[0][kc], bh1, acc[0][1], 0, 0, 0);
                acc[1][0] = __builtin_amdgcn_mfma_f32_16x16x32_bf16(ah[1][kc], bh0, acc[1][0], 0, 0, 0);
                acc[1][1] = __builtin_amdgcn_mfma_f32_16x16x32_bf16(ah[1][kc], bh1, acc[1][1], 0, 0, 0);
            }

#pragma unroll
            for (int i = 0; i < 2; ++i)
#pragma unroll
                for (int r = 0; r < 4; ++r) {
                    float e0 = EXPSH(acc[i][0][r]);
                    float e1 = EXPSH(acc[i][1][r]);
                    ssum[i][r] += e0 + e1;
                }
            // diagonal: row==col  <=>  ch==w, j==i, ml==quad*4+r
            if (dblk && ch == w) {
#pragma unroll
                for (int r = 0; r < 4; ++r)
                    if (ml == (quad << 2) + r)
                        dsum += acc[0][0][r] + acc[1][1][r];
            }
        }

#pragma unroll
        for (int i = 0; i < 2; ++i)
#pragma unroll
            for (int r = 0; r < 4; ++r) {
                float v = ssum[i][r];
#pragma unroll
                for (int o = 1; o < 16; o <<= 1) v += __shfl_xor(v, o, 64);
                if (ml == 0)
                    atomicAdd(S + (size_t)t * BN + rbase + (i << 4) + r, v);
            }
        if (dblk) {
            float dv = dsum;
#pragma unroll
            for (int o = 1; o < 64; o <<= 1) dv += __shfl_xor(dv, o, 64);
            if (lane == 0) atomicAdd(nce_acc, -dv);
        }
    } else {
        // ---- tot29 path: 128 rows x 128 cols, hi/lo 3-pass ----
        const int idx = ((z - 29) << 6) + ((int)blockIdx.y << 3) + (int)blockIdx.x; // 0..255
        const int rb  = idx >> 4, cb = idx & 15;
        const int r0  = rb << 7, c0 = cb << 7;
        const bool dblk = (rb == cb);

        // stage Rh (32 KB, units 0..2047) + Rl (32 KB, units 2048..4095)
#pragma unroll
        for (int n = 0; n < 8; ++n) {
            const int q    = (w << 3) + n;       // 0..63
            const int U    = (q << 6) | lane;    // 0..4095
            const int colL = (U >> 4) & 127;
            const int half = U >> 11;            // uniform within a wave-instr
            const int g    = ((U & 15) - colL) & 15;
            const u16* src = (half ? Rl : Rh) + (size_t)(c0 + colL) * DHH + g * 8;
            __builtin_amdgcn_global_load_lds((const AS1 u32*)src,
                (AS3 u32*)(&sm[q << 9]), 16, 0, 0);
        }

        short8 ah[4], al[4];
#pragma unroll
        for (int kc = 0; kc < 4; ++kc) {
            size_t o = (size_t)(r0 + (w << 4) + ml) * DHH + (kc << 5) + (quad << 3);
            ah[kc] = *(const short8*)(Gh29 + o);
            al[kc] = *(const short8*)(Gl29 + o);
        }

        float esum[4];
#pragma unroll
        for (int r = 0; r < 4; ++r) esum[r] = 0.f;
        float dsum = 0.f;
        const int rbase = r0 + (w << 4) + (quad << 2);   // + r

        __syncthreads();                 // the only barrier

#pragma unroll
        for (int ch = 0; ch < 4; ++ch) {
            f32x4 acc[2];
            acc[0] = (f32x4){0.f, 0.f, 0.f, 0.f};
            acc[1] = (f32x4){0.f, 0.f, 0.f, 0.f};
#pragma unroll
            for (int kc = 0; kc < 4; ++kc) {
                const int slot = ((kc << 2) + quad + ml) & 15;
                const int i0 = ((ch << 5) + ml) * 128 + (slot << 3);
                const int i1 = i0 + 16 * 128;
                const short8 bh0 = *(const short8*)&sm[i0];
                const short8 bl0 = *(const short8*)&sm[16384 + i0];
                const short8 bh1 = *(const short8*)&sm[i1];
                const short8 bl1 = *(const short8*)&sm[16384 + i1];
                acc[0] = __builtin_amdgcn_mfma_f32_16x16x32_bf16(ah[kc], bh0, acc[0], 0, 0, 0);
                acc[0] = __builtin_amdgcn_mfma_f32_16x16x32_bf16(ah[kc], bl0, acc[0], 0, 0, 0);
                acc[0] = __builtin_amdgcn_mfma_f32_16x16x32_bf16(al[kc], bh0, acc[0], 0, 0, 0);
                acc[1] = __builtin_amdgcn_mfma_f32_16x16x32_bf16(ah[kc], bh1, acc[1], 0, 0, 0);
                acc[1] = __builtin_amdgcn_mfma_f32_16x16x32_bf16(ah[kc], bl1, acc[1], 0, 0, 0);
                acc[1] = __builtin_amdgcn_mfma_f32_16x16x32_bf16(al[kc], bh1, acc[1], 0, 0, 0);
            }

#pragma unroll
            for (int j = 0; j < 2; ++j)
#pragma unroll
                for (int r = 0; r < 4; ++r) {
                    float v = acc[j][r];
                    int row = rbase + r;
                    int col = c0 + (ch << 5) + (j << 4) + ml;
                    tot29[(size_t)row * BN + col] = v;
                    esum[r] += EXPSH(v);
                }
            // diagonal: ch==w>>1, j==w&1, ml==quad*4+r
            if (dblk && ch == (w >> 1)) {
#pragma unroll
                for (int r = 0; r < 4; ++r)
                    if (ml == (quad << 2) + r)
                        dsum += (w & 1) ? acc[1][r] : acc[0][r];
            }
        }

#pragma unroll
        for (int r = 0; r < 4; ++r) {
            float v = esum[r];
#pragma unroll
            for (int o = 1; o < 16; o <<= 1) v += __shfl_xor(v, o, 64);
            if (ml == 0) atomicAdd(S29 + rbase + r, v);
        }
        if (dblk) {
            float dv = dsum;
#pragma unroll
            for (int o = 1; o < 64; o <<= 1) dv += __shfl_xor(dv, o, 64);
            if (lane == 0) atomicAdd(nce_acc, -dv);
        }
    }
}

// ---------------- argmax + S-reduce + count + final outputs ----------------
__device__ __forceinline__ u32 fenc(float f) {
    u32 u = __float_as_uint(f);
    return (u & 0x80000000u) ? ~u : (u | 0x80000000u);
}

__global__ __launch_bounds__(256) void argmax_fin_kernel(
    const float* __restrict__ tot29, const float* __restrict__ S,
    u64* __restrict__ table, u32* __restrict__ done,
    float* __restrict__ nce_acc, float* __restrict__ out)
{
    __shared__ float lse_s[128];
    __shared__ float part[4];
    __shared__ u32 lastflag;
    __shared__ int cpart[4];
    const int tid = threadIdx.x;
    const int c   = blockIdx.x * 256 + tid;
    const int b0  = blockIdx.y * 128;
    const float* S29 = S + (size_t)(T_PRED - 1) * BN;

    // S-reduce chunk: 128 blocks x 480 entries = 61440
    {
        const int base = ((int)blockIdx.y * 8 + (int)blockIdx.x) * 480;
        float v = 0.f;
        for (int i = tid; i < 480; i += 256)
            v += ESHIFT + __logf(S[base + i]);
#pragma unroll
        for (int o = 1; o < 64; o <<= 1) v += __shfl_xor(v, o, 64);
        if ((tid & 63) == 0) part[tid >> 6] = v;
        __syncthreads();
        if (tid == 0)
            atomicAdd(nce_acc, part[0] + part[1] + part[2] + part[3]);
    }

    if (tid < 128) lse_s[tid] = ESHIFT + __logf(S29[b0 + tid]);
    __syncthreads();

    float best = -3.4e38f; int bi = 0;
    for (int b = 0; b < 128; ++b) {
        float v = tot29[(size_t)(b0 + b) * BN + c] - lse_s[b];
        if (v > best) { best = v; bi = b0 + b; }
    }
    u64 key = ((u64)fenc(best) << 32) | (u32)(0xFFFFFFFFu - (u32)bi);
    atomicMax(table + c, key);

    __threadfence();
    if (tid == 0) lastflag = (atomicAdd(done, 1u) == 127u);
    __syncthreads();
    if (!lastflag) return;

    int cnt = 0;
    for (int i = tid; i < BN; i += 256) {
        u64 k = atomicAdd(table + i, 0ull);      // device-coherent read
        u32 b = 0xFFFFFFFFu - (u32)(k & 0xFFFFFFFFull);
        if ((int)b == i) cnt++;
    }
#pragma unroll
    for (int o = 1; o < 64; o <<= 1) cnt += __shfl_xor(cnt, o, 64);
    if ((tid & 63) == 0) cpart[tid >> 6] = cnt;
    __syncthreads();
    if (tid == 0) {
        int correct = cpart[0] + cpart[1] + cpart[2] + cpart[3];
        float nce = atomicAdd(nce_acc, 0.0f);
        out[0] = (float)correct / (float)BN;
        out[1] = nce / (float)(BN * T_PRED);
        out[2] = (float)BN;
        out[3] = (float)(BN * T_PRED);
    }
}

extern "C" void kernel_launch(void* const* d_in, const int* in_sizes, int n_in,
                              void* d_out, int out_size, void* d_ws, size_t ws_size,
                              hipStream_t stream) {
    const float* E   = (const float*)d_in[0];   // [T,B,D]
    const float* rep = (const float*)d_in[1];   // [B,DH]
    const float* Ww  = (const float*)d_in[2];   // [T,D,DH]
    float* out = (float*)d_out;

    char* ws = (char*)d_ws;
    float* nce_acc = (float*)(ws + 0);
    u32*   done    = (u32*)(ws + 8);
    float* S       = (float*)(ws + WS_S);
    u64*   table   = (u64*)(ws + WS_TABLE);
    u16*   Wh      = (u16*)(ws + WS_WH);
    u16*   Wl      = (u16*)(ws + WS_WL);
    u16*   Rh      = (u16*)(ws + WS_RH);
    u16*   Rl      = (u16*)(ws + WS_RL);
    u16*   Gh      = (u16*)(ws + WS_GH);
    u16*   Gh29    = Gh + (size_t)(T_PRED - 1) * BN * DHH;
    u16*   Gl29    = (u16*)(ws + WS_GL29);
    float* tot29   = (float*)(ws + WS_T29);

    prep_kernel<<<dim3(128), 256, 0, stream>>>(rep, Ww, Rh, Rl, Wh, Wl, (u32*)ws);
    g_fused_kernel<<<dim3(16, 30), 512, 0, stream>>>(E, Wh, Wl, Gh, Gh29, Gl29);
    nce_fused_kernel<<<dim3(8, 8, 33), 512, 0, stream>>>(Gh, Gh29, Gl29, Rh, Rl,
                                                         S, tot29, nce_acc);
    argmax_fin_kernel<<<dim3(8, 16), 256, 0, stream>>>(tot29, S, table, done,
                                                       nce_acc, out);
}

// Round 13
// 183.618 us; speedup vs baseline: 1.6006x; 1.6006x over previous
//
#include <hip/hip_runtime.h>
#include <math.h>

typedef unsigned short u16;
typedef unsigned int   u32;
typedef unsigned long long u64;

#define T_PRED 30
#define BN 2048
#define DD 256
#define DHH 128
#define ESHIFT 64.0f

typedef __attribute__((ext_vector_type(8))) short short8;   // 8 x bf16
typedef __attribute__((ext_vector_type(4))) float f32x4;

// exp(v - ESHIFT) as one fma + one v_exp  (fallback: sub+mul+exp)
#if defined(__has_builtin)
#if __has_builtin(__builtin_amdgcn_exp2f)
#define EXPSH(v) __builtin_amdgcn_exp2f(__builtin_fmaf((v), 1.44269504f, -92.3324826f))
#endif
#endif
#ifndef EXPSH
#define EXPSH(v) __expf((v) - ESHIFT)
#endif

// ---- workspace layout (~38.3 MB) ----
// 0: f32 nce_acc | 8: u32 done
#define WS_S      4096                     // f32 S[30][2048] fixed-shift exp sums
#define WS_TABLE  (WS_S + 245760)          // u64 table[2048]
#define WS_ZEND   (WS_TABLE + 16384)       // end of zeroed region = 266240 B
#define WS_WH     WS_ZEND                  // u16 W^T hi [30][128][256]
#define WS_WL     (WS_WH + 1966080)        // u16 W^T lo (t=29 slot used)
#define WS_RH     (WS_WL + 1966080)        // u16 rep hi [2048][128]
#define WS_RL     (WS_RH + 524288)
#define WS_GH     (WS_RL + 524288)         // u16 G hi [30][2048][128]
#define WS_GL29   (WS_GH + 15728640)       // u16 G lo (t=29) [2048][128]
#define WS_T29    (WS_GL29 + 524288)       // f32 tot29 [2048][2048]

__device__ __forceinline__ u16 bf16_rne(float f) {
    u32 u = __float_as_uint(f);
    u32 r = u + 0x7fffu + ((u >> 16) & 1u);
    return (u16)(r >> 16);
}

__device__ __forceinline__ short8 pack_hi8(const float* f) {   // truncation split
    short8 r;
#pragma unroll
    for (int k = 0; k < 8; ++k) r[k] = (short)(u16)(__float_as_uint(f[k]) >> 16);
    return r;
}
__device__ __forceinline__ short8 pack_lo8(const float* f) {
    short8 r;
#pragma unroll
    for (int k = 0; k < 8; ++k) {
        float hf = __uint_as_float(__float_as_uint(f[k]) & 0xffff0000u);
        r[k] = (short)bf16_rne(f[k] - hf);
    }
    return r;
}

#define AS1 __attribute__((address_space(1)))
#define AS3 __attribute__((address_space(3)))

// ---------------- prep: zero accumulators + W transpose/split + rep split --
__global__ __launch_bounds__(256) void prep_kernel(
    const float* __restrict__ rep, const float* __restrict__ Ww,
    u16* __restrict__ Rh, u16* __restrict__ Rl,
    u16* __restrict__ Wh, u16* __restrict__ Wl, u32* __restrict__ wsz)
{
    const int bx = blockIdx.x, tid = threadIdx.x;
    // zero nce_acc/done/S/table: 266240 B = 66560 words over 32768 threads
    for (int i = bx * 256 + tid; i < 66560; i += 32768) wsz[i] = 0;

    if (bx < 120) {
        __shared__ float tile[64][132];
        const int t = bx >> 2, d0 = (bx & 3) * 64;
        for (int it = 0; it < 8; ++it) {
            int idx = tid + it * 256;
            int row = idx >> 5, off = (idx & 31) * 4;
            *(float4*)&tile[row][off] =
                *(const float4*)&Ww[((size_t)t * DD + d0 + row) * DHH + off];
        }
        __syncthreads();
        const int h = tid >> 1, half = tid & 1;    // h 0..127, d-half 0..1
        const bool lo = (t == T_PRED - 1);
        for (int d4 = 0; d4 < 32; d4 += 4) {
            ushort4 hv, lv;
            u16* hp = (u16*)&hv; u16* lp = (u16*)&lv;
#pragma unroll
            for (int k = 0; k < 4; ++k) {
                float v = tile[half * 32 + d4 + k][h];
                u16 hb = bf16_rne(v);
                hp[k] = hb;
                float hf = __uint_as_float((u32)hb << 16);
                lp[k] = bf16_rne(v - hf);
            }
            size_t o = (size_t)t * DHH * DD + (size_t)h * DD + d0 + half * 32 + d4;
            *(ushort4*)&Wh[o] = hv;
            if (lo) *(ushort4*)&Wl[o] = lv;
        }
    } else {
        int base = (bx - 120) * 256 + tid;            // float4 index, 8 blocks
        for (int p = 0; p < 32; ++p) {
            int i = base + p * 2048;
            float4 v = ((const float4*)rep)[i];
            float vv[4] = {v.x, v.y, v.z, v.w};
            u16 h[4], l[4];
#pragma unroll
            for (int k = 0; k < 4; ++k) {
                h[k] = bf16_rne(vv[k]);
                float hf = __uint_as_float((u32)h[k] << 16);
                l[k] = bf16_rne(vv[k] - hf);
            }
            ((ushort4*)Rh)[i] = make_ushort4(h[0], h[1], h[2], h[3]);
            ((ushort4*)Rl)[i] = make_ushort4(l[0], l[1], l[2], l[3]);
        }
    }
}

// ---------------- g_fused: ROUND-1 version (~32us inferred; 3 redesigns
// all regressed: R2 +9, R5 +9, R12 +107 — dbuf pipeline + per-kc barriers
// beats single-barrier here because E has ZERO reuse, only W is shared) ----
// y<29 -> G[t] 1-pass 128x128 dbuf; y>=29 -> G[29] 3-pass split.
// grid (16, 33), 256 thr.
__global__ __launch_bounds__(256) void g_fused_kernel(
    const float* __restrict__ E, const u16* __restrict__ Wh,
    const u16* __restrict__ Wl, u16* __restrict__ Gh,
    u16* __restrict__ Gh29, u16* __restrict__ Gl29)
{
    __shared__ __attribute__((aligned(16))) u32 esm[2][4096];   // 2 x 16 KB
    __shared__ __attribute__((aligned(16))) u16 wsm[2][4096];   // 2 x 8 KB
    const int y    = blockIdx.y;
    const int tid  = threadIdx.x;
    const int lane = tid & 63;
    const int w    = tid >> 6;
    const int ml   = lane & 15;
    const int quad = lane >> 4;

    if (y < 29) {
        const int t    = y;
        const int row0 = blockIdx.x * 128;
        const int wr   = (w >> 1) * 64;
        const int wc   = (w & 1) * 64;
        const float* Et = E + (size_t)t * BN * DD;
        const u16*   Wt = Wh + (size_t)t * DHH * DD;
        const int erow_l = lane >> 3, eunit = lane & 7;
        const int wcol_l = lane >> 2, wunit = lane & 3;

        auto stage = [&](int buf, int kc) {
#pragma unroll
            for (int n = 0; n < 4; ++n) {                  // E: 16 instrs
                int q = w * 4 + n;
                int row = q * 8 + erow_l;
                int unit = (eunit - row) & 7;
                const float* g = Et + (size_t)(row0 + row) * DD + kc * 32 + unit * 4;
                __builtin_amdgcn_global_load_lds((const AS1 u32*)g,
                    (AS3 u32*)(&esm[buf][q * 256]), 16, 0, 0);
            }
#pragma unroll
            for (int n = 0; n < 2; ++n) {                  // W: 8 instrs
                int q = w * 2 + n;
                int col = q * 16 + wcol_l;
                int unit = (wunit - col) & 3;
                const u16* g = Wt + (size_t)col * DD + kc * 32 + unit * 8;
                __builtin_amdgcn_global_load_lds((const AS1 u32*)g,
                    (AS3 u32*)(&wsm[buf][q * 512]), 16, 0, 0);
            }
        };

        f32x4 acc[4][4];
#pragma unroll
        for (int i = 0; i < 4; ++i)
#pragma unroll
            for (int j = 0; j < 4; ++j) acc[i][j] = (f32x4){0.f, 0.f, 0.f, 0.f};

        stage(0, 0);
        __syncthreads();
#pragma unroll 1
        for (int kc = 0; kc < 8; ++kc) {
            if (kc < 7) stage((kc + 1) & 1, kc + 1);
            const int pb = kc & 1;
            short8 ah[4], bh[4];
#pragma unroll
            for (int i = 0; i < 4; ++i) {
                int row = wr + i * 16 + ml;
                float4 f0 = *(const float4*)&esm[pb][row * 32 + (((quad * 2 + 0 + row) & 7) * 4)];
                float4 f1 = *(const float4*)&esm[pb][row * 32 + (((quad * 2 + 1 + row) & 7) * 4)];
                float f[8] = {f0.x, f0.y, f0.z, f0.w, f1.x, f1.y, f1.z, f1.w};
                ah[i] = pack_hi8(f);
            }
#pragma unroll
            for (int j = 0; j < 4; ++j) {
                int col = wc + j * 16 + ml;
                bh[j] = *(const short8*)&wsm[pb][col * 32 + ((quad + col) & 3) * 8];
            }
#pragma unroll
            for (int i = 0; i < 4; ++i)
#pragma unroll
                for (int j = 0; j < 4; ++j)
                    acc[i][j] = __builtin_amdgcn_mfma_f32_16x16x32_bf16(ah[i], bh[j], acc[i][j], 0, 0, 0);
            __syncthreads();
        }

#pragma unroll
        for (int i = 0; i < 4; ++i)
#pragma unroll
            for (int j = 0; j < 4; ++j)
#pragma unroll
                for (int r = 0; r < 4; ++r) {
                    int row = row0 + wr + i * 16 + quad * 4 + r;
                    int col = wc + j * 16 + ml;
                    Gh[((size_t)t * BN + row) * DHH + col] = bf16_rne(acc[i][j][r]);
                }
    } else {
        // t=29 3-pass split, rows row0..row0+32, wave w -> cols w*32..+32
        const int row0 = ((y - 29) * 16 + blockIdx.x) * 32;
        const int wc   = w * 32;
        const size_t tE = (size_t)(T_PRED - 1) * BN * DD;
        const size_t tW = (size_t)(T_PRED - 1) * DHH * DD;

#pragma unroll 1
        for (int rr = 0; rr < 32; rr += 16) {
            f32x4 acc[2];
            acc[0] = (f32x4){0.f, 0.f, 0.f, 0.f};
            acc[1] = (f32x4){0.f, 0.f, 0.f, 0.f};
#pragma unroll
            for (int kc = 0; kc < 8; ++kc) {
                const float* ep = E + tE + (size_t)(row0 + rr + ml) * DD + kc * 32 + quad * 8;
                float4 e0 = *(const float4*)ep;
                float4 e1 = *(const float4*)(ep + 4);
                float f[8] = {e0.x, e0.y, e0.z, e0.w, e1.x, e1.y, e1.z, e1.w};
                short8 ah = pack_hi8(f);
                short8 al = pack_lo8(f);
#pragma unroll
                for (int j = 0; j < 2; ++j) {
                    size_t o = tW + (size_t)(wc + j * 16 + ml) * DD + kc * 32 + quad * 8;
                    short8 bh = *(const short8*)(Wh + o);
                    short8 bl = *(const short8*)(Wl + o);
                    acc[j] = __builtin_amdgcn_mfma_f32_16x16x32_bf16(ah, bh, acc[j], 0, 0, 0);
                    acc[j] = __builtin_amdgcn_mfma_f32_16x16x32_bf16(ah, bl, acc[j], 0, 0, 0);
                    acc[j] = __builtin_amdgcn_mfma_f32_16x16x32_bf16(al, bh, acc[j], 0, 0, 0);
                }
            }
#pragma unroll
            for (int j = 0; j < 2; ++j)
#pragma unroll
                for (int r = 0; r < 4; ++r) {
                    int row = row0 + rr + quad * 4 + r;
                    int col = wc + j * 16 + ml;
                    float v = acc[j][r];
                    u16 hb = bf16_rne(v);
                    float hf = __uint_as_float((u32)hb << 16);
                    Gh29[(size_t)row * DHH + col] = hb;
                    Gl29[(size_t)row * DHH + col] = bf16_rne(v - hf);
                }
        }
    }
}

// ---------------- nce_fused v9 (best measured: 52.6us) ---------------------
// 512-thr, grid (8,8,33), 64KB LDS, single stage + single barrier.
// r0 <- blockIdx.x / c0 <- blockIdx.y: XCD-locality swizzle (FETCH 64->14MB).
// Frozen: all intra-block variants measured equal or worse (R3,R5-R8,R10).
__global__ __launch_bounds__(512, 4) void nce_fused_kernel(
    const u16* __restrict__ Gh, const u16* __restrict__ Gh29,
    const u16* __restrict__ Gl29, const u16* __restrict__ Rh,
    const u16* __restrict__ Rl, float* __restrict__ S,
    float* __restrict__ tot29, float* __restrict__ nce_acc)
{
    __shared__ __attribute__((aligned(16))) u16 sm[32768];   // 64 KB
    const int z    = blockIdx.z;
    const int tid  = threadIdx.x;
    const int lane = tid & 63;
    const int w    = tid >> 6;          // 0..7
    const int ml   = lane & 15;
    const int quad = lane >> 4;
    float* S29 = S + (size_t)(T_PRED - 1) * BN;

    if (z < 29) {
        const int t  = z;
        const int c0 = (int)blockIdx.y << 8;     // col block (256)
        const int r0 = (int)blockIdx.x << 8;     // row block (256)

        // ---- stage Rh[c0..c0+256) -> LDS, rotate-swizzled, once ----
#pragma unroll
        for (int n = 0; n < 8; ++n) {
            const int q   = (w << 3) + n;        // 0..63 wave-instrs
            const int U   = (q << 6) | lane;     // 0..4095
            const int col = U >> 4;
            const int g   = ((U & 15) - col) & 15;
            const u16* src = Rh + (size_t)(c0 + col) * DHH + g * 8;
            __builtin_amdgcn_global_load_lds((const AS1 u32*)src,
                (AS3 u32*)(&sm[q << 9]), 16, 0, 0);
        }

        // ---- A fragments: 32 rows/wave, held in registers ----
        short8 ah[2][4];
#pragma unroll
        for (int i = 0; i < 2; ++i)
#pragma unroll
            for (int kc = 0; kc < 4; ++kc)
                ah[i][kc] = *(const short8*)(Gh +
                    ((size_t)t * BN + r0 + (w << 5) + (i << 4) + ml) * DHH
                    + (kc << 5) + (quad << 3));

        float ssum[2][4];
#pragma unroll
        for (int i = 0; i < 2; ++i)
#pragma unroll
            for (int r = 0; r < 4; ++r) ssum[i][r] = 0.f;
        float dsum = 0.f;
        const bool dblk = (c0 == r0);
        const int rbase = r0 + (w << 5) + (quad << 2);   // + i*16 + r

        __syncthreads();                 // the only barrier

#pragma unroll 2
        for (int ch = 0; ch < 8; ++ch) {
            f32x4 acc[2][2];
#pragma unroll
            for (int i = 0; i < 2; ++i)
#pragma unroll
                for (int j = 0; j < 2; ++j) acc[i][j] = (f32x4){0.f, 0.f, 0.f, 0.f};

#pragma unroll
            for (int kc = 0; kc < 4; ++kc) {
                const int slot = ((kc << 2) + quad + ml) & 15;
                const short8 bh0 = *(const short8*)&sm[((ch << 5) + ml) * 128 + (slot << 3)];
                const short8 bh1 = *(const short8*)&sm[((ch << 5) + 16 + ml) * 128 + (slot << 3)];
                acc[0][0] = __builtin_amdgcn_mfma_f32_16x16x32_bf16(ah[0][kc], bh0, acc[0][0], 0, 0, 0);
                acc[0][1] = __builtin_amdgcn_mfma_f32_16x16x32_bf16(ah[0][kc], bh1, acc[0][1], 0, 0, 0);
                acc[1][0] = __builtin_amdgcn_mfma_f32_16x16x32_bf16(ah[1][kc], bh0, acc[1][0], 0, 0, 0);
                acc[1][1] = __builtin_amdgcn_mfma_f32_16x16x32_bf16(ah[1][kc], bh1, acc[1][1], 0, 0, 0);
            }

#pragma unroll
            for (int i = 0; i < 2; ++i)
#pragma unroll
                for (int r = 0; r < 4; ++r) {
                    float e0 = EXPSH(acc[i][0][r]);
                    float e1 = EXPSH(acc[i][1][r]);
                    ssum[i][r] += e0 + e1;
                }
            // diagonal: row==col  <=>  ch==w, j==i, ml==quad*4+r
            if (dblk && ch == w) {
#pragma unroll
                for (int r = 0; r < 4; ++r)
                    if (ml == (quad << 2) + r)
                        dsum += acc[0][0][r] + acc[1][1][r];
            }
        }

#pragma unroll
        for (int i = 0; i < 2; ++i)
#pragma unroll
            for (int r = 0; r < 4; ++r) {
                float v = ssum[i][r];
#pragma unroll
                for (int o = 1; o < 16; o <<= 1) v += __shfl_xor(v, o, 64);
                if (ml == 0)
                    atomicAdd(S + (size_t)t * BN + rbase + (i << 4) + r, v);
            }
        if (dblk) {
            float dv = dsum;
#pragma unroll
            for (int o = 1; o < 64; o <<= 1) dv += __shfl_xor(dv, o, 64);
            if (lane == 0) atomicAdd(nce_acc, -dv);
        }
    } else {
        // ---- tot29 path: 128 rows x 128 cols, hi/lo 3-pass ----
        const int idx = ((z - 29) << 6) + ((int)blockIdx.y << 3) + (int)blockIdx.x; // 0..255
        const int rb  = idx >> 4, cb = idx & 15;
        const int r0  = rb << 7, c0 = cb << 7;
        const bool dblk = (rb == cb);

        // stage Rh (32 KB, units 0..2047) + Rl (32 KB, units 2048..4095)
#pragma unroll
        for (int n = 0; n < 8; ++n) {
            const int q    = (w << 3) + n;       // 0..63
            const int U    = (q << 6) | lane;    // 0..4095
            const int colL = (U >> 4) & 127;
            const int half = U >> 11;            // uniform within a wave-instr
            const int g    = ((U & 15) - colL) & 15;
            const u16* src = (half ? Rl : Rh) + (size_t)(c0 + colL) * DHH + g * 8;
            __builtin_amdgcn_global_load_lds((const AS1 u32*)src,
                (AS3 u32*)(&sm[q << 9]), 16, 0, 0);
        }

        short8 ah[4], al[4];
#pragma unroll
        for (int kc = 0; kc < 4; ++kc) {
            size_t o = (size_t)(r0 + (w << 4) + ml) * DHH + (kc << 5) + (quad << 3);
            ah[kc] = *(const short8*)(Gh29 + o);
            al[kc] = *(const short8*)(Gl29 + o);
        }

        float esum[4];
#pragma unroll
        for (int r = 0; r < 4; ++r) esum[r] = 0.f;
        float dsum = 0.f;
        const int rbase = r0 + (w << 4) + (quad << 2);   // + r

        __syncthreads();                 // the only barrier

#pragma unroll
        for (int ch = 0; ch < 4; ++ch) {
            f32x4 acc[2];
            acc[0] = (f32x4){0.f, 0.f, 0.f, 0.f};
            acc[1] = (f32x4){0.f, 0.f, 0.f, 0.f};
#pragma unroll
            for (int kc = 0; kc < 4; ++kc) {
                const int slot = ((kc << 2) + quad + ml) & 15;
                const int i0 = ((ch << 5) + ml) * 128 + (slot << 3);
                const int i1 = i0 + 16 * 128;
                const short8 bh0 = *(const short8*)&sm[i0];
                const short8 bl0 = *(const short8*)&sm[16384 + i0];
                const short8 bh1 = *(const short8*)&sm[i1];
                const short8 bl1 = *(const short8*)&sm[16384 + i1];
                acc[0] = __builtin_amdgcn_mfma_f32_16x16x32_bf16(ah[kc], bh0, acc[0], 0, 0, 0);
                acc[0] = __builtin_amdgcn_mfma_f32_16x16x32_bf16(ah[kc], bl0, acc[0], 0, 0, 0);
                acc[0] = __builtin_amdgcn_mfma_f32_16x16x32_bf16(al[kc], bh0, acc[0], 0, 0, 0);
                acc[1] = __builtin_amdgcn_mfma_f32_16x16x32_bf16(ah[kc], bh1, acc[1], 0, 0, 0);
                acc[1] = __builtin_amdgcn_mfma_f32_16x16x32_bf16(ah[kc], bl1, acc[1], 0, 0, 0);
                acc[1] = __builtin_amdgcn_mfma_f32_16x16x32_bf16(al[kc], bh1, acc[1], 0, 0, 0);
            }

#pragma unroll
            for (int j = 0; j < 2; ++j)
#pragma unroll
                for (int r = 0; r < 4; ++r) {
                    float v = acc[j][r];
                    int row = rbase + r;
                    int col = c0 + (ch << 5) + (j << 4) + ml;
                    tot29[(size_t)row * BN + col] = v;
                    esum[r] += EXPSH(v);
                }
            // diagonal: ch==w>>1, j==w&1, ml==quad*4+r
            if (dblk && ch == (w >> 1)) {
#pragma unroll
                for (int r = 0; r < 4; ++r)
                    if (ml == (quad << 2) + r)
                        dsum += (w & 1) ? acc[1][r] : acc[0][r];
            }
        }

#pragma unroll
        for (int r = 0; r < 4; ++r) {
            float v = esum[r];
#pragma unroll
            for (int o = 1; o < 16; o <<= 1) v += __shfl_xor(v, o, 64);
            if (ml == 0) atomicAdd(S29 + rbase + r, v);
        }
        if (dblk) {
            float dv = dsum;
#pragma unroll
            for (int o = 1; o < 64; o <<= 1) dv += __shfl_xor(dv, o, 64);
            if (lane == 0) atomicAdd(nce_acc, -dv);
        }
    }
}

// ---------------- argmax + S-reduce + count + final outputs ----------------
__device__ __forceinline__ u32 fenc(float f) {
    u32 u = __float_as_uint(f);
    return (u & 0x80000000u) ? ~u : (u | 0x80000000u);
}

__global__ __launch_bounds__(256) void argmax_fin_kernel(
    const float* __restrict__ tot29, const float* __restrict__ S,
    u64* __restrict__ table, u32* __restrict__ done,
    float* __restrict__ nce_acc, float* __restrict__ out)
{
    __shared__ float lse_s[128];
    __shared__ float part[4];
    __shared__ u32 lastflag;
    __shared__ int cpart[4];
    const int tid = threadIdx.x;
    const int c   = blockIdx.x * 256 + tid;
    const int b0  = blockIdx.y * 128;
    const float* S29 = S + (size_t)(T_PRED - 1) * BN;

    // S-reduce chunk: 128 blocks x 480 entries = 61440
    {
        const int base = ((int)blockIdx.y * 8 + (int)blockIdx.x) * 480;
        float v = 0.f;
        for (int i = tid; i < 480; i += 256)
            v += ESHIFT + __logf(S[base + i]);
#pragma unroll
        for (int o = 1; o < 64; o <<= 1) v += __shfl_xor(v, o, 64);
        if ((tid & 63) == 0) part[tid >> 6] = v;
        __syncthreads();
        if (tid == 0)
            atomicAdd(nce_acc, part[0] + part[1] + part[2] + part[3]);
    }

    if (tid < 128) lse_s[tid] = ESHIFT + __logf(S29[b0 + tid]);
    __syncthreads();

    float best = -3.4e38f; int bi = 0;
    for (int b = 0; b < 128; ++b) {
        float v = tot29[(size_t)(b0 + b) * BN + c] - lse_s[b];
        if (v > best) { best = v; bi = b0 + b; }
    }
    u64 key = ((u64)fenc(best) << 32) | (u32)(0xFFFFFFFFu - (u32)bi);
    atomicMax(table + c, key);

    __threadfence();
    if (tid == 0) lastflag = (atomicAdd(done, 1u) == 127u);
    __syncthreads();
    if (!lastflag) return;

    int cnt = 0;
    for (int i = tid; i < BN; i += 256) {
        u64 k = atomicAdd(table + i, 0ull);      // device-coherent read
        u32 b = 0xFFFFFFFFu - (u32)(k & 0xFFFFFFFFull);
        if ((int)b == i) cnt++;
    }
#pragma unroll
    for (int o = 1; o < 64; o <<= 1) cnt += __shfl_xor(cnt, o, 64);
    if ((tid & 63) == 0) cpart[tid >> 6] = cnt;
    __syncthreads();
    if (tid == 0) {
        int correct = cpart[0] + cpart[1] + cpart[2] + cpart[3];
        float nce = atomicAdd(nce_acc, 0.0f);
        out[0] = (float)correct / (float)BN;
        out[1] = nce / (float)(BN * T_PRED);
        out[2] = (float)BN;
        out[3] = (float)(BN * T_PRED);
    }
}

extern "C" void kernel_launch(void* const* d_in, const int* in_sizes, int n_in,
                              void* d_out, int out_size, void* d_ws, size_t ws_size,
                              hipStream_t stream) {
    const float* E   = (const float*)d_in[0];   // [T,B,D]
    const float* rep = (const float*)d_in[1];   // [B,DH]
    const float* Ww  = (const float*)d_in[2];   // [T,D,DH]
    float* out = (float*)d_out;

    char* ws = (char*)d_ws;
    float* nce_acc = (float*)(ws + 0);
    u32*   done    = (u32*)(ws + 8);
    float* S       = (float*)(ws + WS_S);
    u64*   table   = (u64*)(ws + WS_TABLE);
    u16*   Wh      = (u16*)(ws + WS_WH);
    u16*   Wl      = (u16*)(ws + WS_WL);
    u16*   Rh      = (u16*)(ws + WS_RH);
    u16*   Rl      = (u16*)(ws + WS_RL);
    u16*   Gh      = (u16*)(ws + WS_GH);
    u16*   Gh29    = Gh + (size_t)(T_PRED - 1) * BN * DHH;
    u16*   Gl29    = (u16*)(ws + WS_GL29);
    float* tot29   = (float*)(ws + WS_T29);

    prep_kernel<<<dim3(128), 256, 0, stream>>>(rep, Ww, Rh, Rl, Wh, Wl, (u32*)ws);
    g_fused_kernel<<<dim3(16, 33), 256, 0, stream>>>(E, Wh, Wl, Gh, Gh29, Gl29);
    nce_fused_kernel<<<dim3(8, 8, 33), 512, 0, stream>>>(Gh, Gh29, Gl29, Rh, Rl,
                                                         S, tot29, nce_acc);
    argmax_fin_kernel<<<dim3(8, 16), 256, 0, stream>>>(tot29, S, table, done,
                                                       nce_acc, out);
}